// Round 3
// baseline (292.308 us; speedup 1.0000x reference)
//
#include <hip/hip_runtime.h>

#define B 8
#define N 8192
#define M 2048
#define NITER 4
#define BASE_ALPHA 0.1f
#define MARGIN 0.02f           // covers fp slack (~1e-5) on the NN-invariance bound
#define CAP 16                 // candidate-list capacity (expected count ~2-3)
#define QCAP 1536              // (point,split) work-queue capacity (expected ~640)

#define NTHR 1024              // 16 waves
#define NPT 32                 // point-lanes per split
#define NSPLIT 32              // j-splits per block
#define JS (M / NSPLIT)        // 64 y's per split
#define JQ (JS / 4)            // 16 j-quads per split
#define PT 8                   // points per thread
#define PPB (NPT * PT)         // 256 points per block
#define NBLK (B * N / PPB)     // 256 blocks (iter0)

// ws layout: pos4 float4[B*N] @0 (1MB); mask u32[B*N] @1MB (bit s set iff
// split-s iter-0 min <= d0+MARGIN); cnt u32[B*N] @1.25MB (>CAP => tail uses
// mask-scan fallback); cand u16[B*N][CAP] @1.5MB (2MB), unordered (tail uses
// lex (t,j) min, so slot order is irrelevant).
// NN-invariance: computed argmin at iters 1-3 lies in {j: dist_0(j) <= d_0 +
// MARGIN}: mv = sum(alpha_i*d_i), NN-dist at step u <= d_0 - mv, excluded j
// has dist >= d_0 + MARGIN - mv => loses by >= MARGIN >> fp slack.
#define OFF_MASK  (1024 * 1024)
#define OFF_CNT   (1280 * 1024)
#define OFF_CANDL (1536 * 1024)

typedef float f2 __attribute__((ext_vector_type(2)));

// ---------------- iter 0: full scan + candidate-list emission ----------------
__global__ __launch_bounds__(NTHR, 8) void iter_kernel(const float* __restrict__ pred,
                                                       const float* __restrict__ partial,
                                                       float4* __restrict__ pos4,
                                                       unsigned int* __restrict__ maskbuf,
                                                       unsigned int* __restrict__ gcnt,
                                                       unsigned short* __restrict__ gcand) {
    __shared__ float4 sX[M / 4], sY[M / 4], sZ[M / 4], sW[M / 4];  // 32 KB
    __shared__ float smint[NSPLIT][PPB];                           // 32 KB
    __shared__ float4 lpos[PPB];                                   // 4 KB
    __shared__ float thrsh[PPB];                                   // 1 KB
    __shared__ unsigned int queue[QCAP];                           // 6 KB
    __shared__ unsigned int qn;

    const int tid = threadIdx.x;
    const int b = blockIdx.x >> 5;
    const int blk = blockIdx.x & 31;
    const int gp0 = b * N + blk * PPB;

    if (tid == 0) qn = 0;

    // Build SoA tile. (-2y)*x bit-equal to reference's (-2x)*y.
    const float* pa = partial + b * M * 3;
    if (tid < M / 4) {
        int sp = tid & 31, jq = tid >> 5;
        const float* p0 = pa + (sp * JS + jq * 4) * 3;
        float a0 = p0[0], a1 = p0[1],  a2 = p0[2];
        float b0 = p0[3], b1 = p0[4],  b2 = p0[5];
        float c0 = p0[6], c1 = p0[7],  c2 = p0[8];
        float d0 = p0[9], d1 = p0[10], d2 = p0[11];
        sX[tid] = make_float4(-2.f * a0, -2.f * b0, -2.f * c0, -2.f * d0);
        sY[tid] = make_float4(-2.f * a1, -2.f * b1, -2.f * c1, -2.f * d1);
        sZ[tid] = make_float4(-2.f * a2, -2.f * b2, -2.f * c2, -2.f * d2);
        sW[tid] = make_float4(a0 * a0 + a1 * a1 + a2 * a2, b0 * b0 + b1 * b1 + b2 * b2,
                              c0 * c0 + c1 * c1 + c2 * c2, d0 * d0 + d1 * d1 + d2 * d2);
    }

    // Owners: refined_0 = pred.
    if (tid < PPB) {
        const int p = gp0 + tid;
        const float* pp = pred + (unsigned long long)p * 3;
        float rx = pp[0], ry = pp[1], rz = pp[2];
        float w = rx * rx + ry * ry + rz * rz;
        lpos[tid] = make_float4(rx, ry, rz, w);
        pos4[p] = make_float4(rx, ry, rz, w);
    }
    __syncthreads();

    const int split = tid >> 5;                    // 0..31 (uniform per half-wave)
    const int pt = tid & 31;

    // ---- pass 1: packed-f32 per-split min ----
    f2 sx[PT], sy[PT], sz[PT];
    #pragma unroll
    for (int k = 0; k < PT; ++k) {
        float4 r = lpos[pt + k * NPT];
        sx[k] = (f2){r.x, r.x}; sy[k] = (f2){r.y, r.y}; sz[k] = (f2){r.z, r.z};
    }
    f2 acc[PT];
    #pragma unroll
    for (int k = 0; k < PT; ++k) acc[k] = (f2){3.402823466e+38f, 3.402823466e+38f};

    #pragma unroll 2
    for (int jq = 0; jq < JQ; ++jq) {
        float4 qx = sX[jq * 32 + split], qy = sY[jq * 32 + split];
        float4 qz = sZ[jq * 32 + split], qw = sW[jq * 32 + split];
        f2 qx01 = (f2){qx.x, qx.y}, qx23 = (f2){qx.z, qx.w};
        f2 qy01 = (f2){qy.x, qy.y}, qy23 = (f2){qy.z, qy.w};
        f2 qz01 = (f2){qz.x, qz.y}, qz23 = (f2){qz.z, qz.w};
        f2 qw01 = (f2){qw.x, qw.y}, qw23 = (f2){qw.z, qw.w};
        #pragma unroll
        for (int k = 0; k < PT; ++k) {
            f2 t01 = __builtin_elementwise_fma(sx[k], qx01,
                     __builtin_elementwise_fma(sy[k], qy01,
                     __builtin_elementwise_fma(sz[k], qz01, qw01)));
            f2 t23 = __builtin_elementwise_fma(sx[k], qx23,
                     __builtin_elementwise_fma(sy[k], qy23,
                     __builtin_elementwise_fma(sz[k], qz23, qw23)));
            acc[k] = __builtin_elementwise_min(acc[k],
                     __builtin_elementwise_min(t01, t23));     // exact, order-invariant
        }
    }
    #pragma unroll
    for (int k = 0; k < PT; ++k)
        smint[split][pt + k * NPT] = fminf(acc[k].x, acc[k].y);
    __syncthreads();

    // ---- owners: threshold + mask + (point,split) work-queue ----
    if (tid < PPB) {
        float tstar = 3.402823466e+38f;
        #pragma unroll
        for (int s = 0; s < NSPLIT; ++s) tstar = fminf(tstar, smint[s][tid]);
        const float4 f4 = lpos[tid];
        const float md = sqrtf(fmaxf(f4.w + tstar, 0.0f));
        float mdm = md + MARGIN;
        float thr = fmaf(mdm, mdm, -f4.w);         // dist<=md+MARGIN <=> t<=thr
        thrsh[tid] = thr;
        gcnt[gp0 + tid] = 0u;
        unsigned int mask = 0u;
        #pragma unroll
        for (int s = 0; s < NSPLIT; ++s) {
            if (smint[s][tid] <= thr) {
                mask |= (1u << s);
                unsigned int q = atomicAdd(&qn, 1u);
                if (q < QCAP) queue[q] = ((unsigned int)tid << 5) | (unsigned int)s;
                else gcnt[gp0 + tid] = 0x40000000u;   // queue overflow -> fallback
            }
        }
        maskbuf[gp0 + tid] = mask;
    }
    __syncthreads();

    // ---- drain queue: uniform 64-j scans, no divergence tax ----
    // Chains here only FILTER (threshold has >> fp-slack margin); tail
    // re-evaluates distances itself, so these need not be bit-anything.
    unsigned int qc = qn; if (qc > QCAP) qc = QCAP;
    for (unsigned int e = tid; e < qc; e += NTHR) {
        unsigned int ent = queue[e];
        int p2 = (int)(ent >> 5), s = (int)(ent & 31u);
        float4 f4 = lpos[p2];
        float thr = thrsh[p2];
        unsigned int* cp = gcnt + (gp0 + p2);
        unsigned long long cb = (unsigned long long)(gp0 + p2) * CAP;
        for (int jq = 0; jq < JQ; ++jq) {
            float4 qx = sX[jq * 32 + s], qy = sY[jq * 32 + s];
            float4 qz = sZ[jq * 32 + s], qw = sW[jq * 32 + s];
            float t0 = fmaf(f4.x, qx.x, fmaf(f4.y, qy.x, fmaf(f4.z, qz.x, qw.x)));
            float t1 = fmaf(f4.x, qx.y, fmaf(f4.y, qy.y, fmaf(f4.z, qz.y, qw.y)));
            float t2 = fmaf(f4.x, qx.z, fmaf(f4.y, qy.z, fmaf(f4.z, qz.z, qw.z)));
            float t3 = fmaf(f4.x, qx.w, fmaf(f4.y, qy.w, fmaf(f4.z, qz.w, qw.w)));
            int j0 = s * JS + jq * 4;
            if (t0 <= thr) { unsigned int sl = atomicAdd(cp, 1u); if (sl < CAP) gcand[cb + sl] = (unsigned short)(j0 + 0); }
            if (t1 <= thr) { unsigned int sl = atomicAdd(cp, 1u); if (sl < CAP) gcand[cb + sl] = (unsigned short)(j0 + 1); }
            if (t2 <= thr) { unsigned int sl = atomicAdd(cp, 1u); if (sl < CAP) gcand[cb + sl] = (unsigned short)(j0 + 2); }
            if (t3 <= thr) { unsigned int sl = atomicAdd(cp, 1u); if (sl < CAP) gcand[cb + sl] = (unsigned short)(j0 + 3); }
        }
    }
}

// NN over candidate list (lex (t,j) min == first-argmin, order-free) with
// masked-split fallback. Eval chain verbatim (bit-identical to pk halves).
__device__ __forceinline__ void nn_eval(float x, float y, float z,
                                        unsigned int c0, unsigned int mk,
                                        const unsigned short* cp,
                                        const float4* sQ,
                                        float& bt_out, int& bj_out) {
    float bt = 3.402823466e+38f; int bj = 0;
    if (c0 <= CAP) {
        for (unsigned int c = 0; c < c0; ++c) {
            int j = cp[c];
            float4 qq = sQ[j];
            float t = fmaf(x, qq.x, fmaf(y, qq.y, fmaf(z, qq.z, qq.w)));
            if (t < bt || (t == bt && j < bj)) { bt = t; bj = j; }
        }
    } else {                                       // rare: masked-split scan
        unsigned int m = mk;
        while (m) {
            int s = __builtin_ctz(m); m &= m - 1;
            int jb = s * JS;
            for (int jj = 0; jj < JS; ++jj) {      // ascending j: strict < = first
                int j = jb + jj;
                float4 qq = sQ[j];
                float t = fmaf(x, qq.x, fmaf(y, qq.y, fmaf(z, qq.z, qq.w)));
                if (t < bt) { bt = t; bj = j; }
            }
        }
    }
    bt_out = bt; bj_out = bj;
}

// ---------------- iters 0..3 NN + 4 updates + final, one block per batch ----
__global__ __launch_bounds__(NTHR, 4) void tail_kernel(const float* __restrict__ partial,
                                                       const float4* __restrict__ pos4,
                                                       const unsigned int* __restrict__ maskbuf,
                                                       const unsigned int* __restrict__ gcnt,
                                                       const unsigned short* __restrict__ gcand,
                                                       float* __restrict__ out) {
    __shared__ float4 sQ[M];       // (-2y0,-2y1,-2y2,|y|^2)  32 KB
    __shared__ float redw[16];
    __shared__ float mxsh;

    const int tid = threadIdx.x;
    const int b = blockIdx.x;

    const float* pa = partial + b * M * 3;
    for (int j = tid; j < M; j += NTHR) {
        float a0 = pa[j * 3 + 0], a1 = pa[j * 3 + 1], a2 = pa[j * 3 + 2];
        sQ[j] = make_float4(-2.f * a0, -2.f * a1, -2.f * a2,
                            a0 * a0 + a1 * a1 + a2 * a2);
    }

    float rx[8], ry[8], rz[8], ww[8], md[8];
    int idx[8];
    unsigned int cnt[8], mk[8];
    #pragma unroll
    for (int k = 0; k < 8; ++k) {
        int p = b * N + k * NTHR + tid;
        float4 f = pos4[p];
        rx[k] = f.x; ry[k] = f.y; rz[k] = f.z; ww[k] = f.w;
        cnt[k] = gcnt[p];
        mk[k] = maskbuf[p];
    }
    __syncthreads();

    // NN at x0 (recomputes iter-0 md/idx bit-exactly: list contains argmin,
    // same fmaf chain as pass-1's pk halves).
    #pragma unroll
    for (int k = 0; k < 8; ++k) {
        int p = b * N + k * NTHR + tid;
        float bt; int bj;
        nn_eval(rx[k], ry[k], rz[k], cnt[k], mk[k],
                gcand + (unsigned long long)p * CAP, sQ, bt, bj);
        md[k] = sqrtf(fmaxf(ww[k] + bt, 0.0f));
        idx[k] = bj;
    }

    for (int u = 0; u < NITER; ++u) {
        // batch max of md (exact: fmax is order-invariant)
        float vm = md[0];
        #pragma unroll
        for (int k = 1; k < 8; ++k) vm = fmaxf(vm, md[k]);
        #pragma unroll
        for (int o = 32; o > 0; o >>= 1) vm = fmaxf(vm, __shfl_xor(vm, o));
        if ((tid & 63) == 0) redw[tid >> 6] = vm;
        __syncthreads();
        if (tid == 0) {
            float v = redw[0];
            #pragma unroll
            for (int r = 1; r < 16; ++r) v = fmaxf(v, redw[r]);
            mxsh = v;
        }
        __syncthreads();

        float inv = 1.0f / (mxsh + 1e-6f);
        #pragma unroll
        for (int k = 0; k < 8; ++k) {
            int p = b * N + k * NTHR + tid;
            float4 q = sQ[idx[k]];
            float ny0 = -0.5f * q.x;               // exact y bits
            float ny1 = -0.5f * q.y;
            float ny2 = -0.5f * q.z;
            float alpha = BASE_ALPHA * (2.0f - md[k] * inv);
            float nx = fmaf(alpha, ny0 - rx[k], rx[k]);
            float nyv = fmaf(alpha, ny1 - ry[k], ry[k]);
            float nz = fmaf(alpha, ny2 - rz[k], rz[k]);
            rx[k] = nx; ry[k] = nyv; rz[k] = nz;
            if (u < NITER - 1) {
                ww[k] = nx * nx + nyv * nyv + nz * nz;
                float bt; int bj;
                nn_eval(nx, nyv, nz, cnt[k], mk[k],
                        gcand + (unsigned long long)p * CAP, sQ, bt, bj);
                md[k] = sqrtf(fmaxf(ww[k] + bt, 0.0f));
                idx[k] = bj;
            } else {
                float* po = out + (unsigned long long)p * 3;
                po[0] = nx; po[1] = nyv; po[2] = nz;
            }
        }
    }
}

extern "C" void kernel_launch(void* const* d_in, const int* in_sizes, int n_in,
                              void* d_out, int out_size, void* d_ws, size_t ws_size,
                              hipStream_t stream) {
    const float* pred = (const float*)d_in[0];
    const float* partial = (const float*)d_in[1];
    char* ws = (char*)d_ws;
    float4* pos4 = (float4*)ws;
    unsigned int* maskb = (unsigned int*)(ws + OFF_MASK);
    unsigned int* gcnt = (unsigned int*)(ws + OFF_CNT);
    unsigned short* gcand = (unsigned short*)(ws + OFF_CANDL);
    float* out = (float*)d_out;

    hipLaunchKernelGGL(iter_kernel, dim3(NBLK), dim3(NTHR), 0, stream,
                       pred, partial, pos4, maskb, gcnt, gcand);
    hipLaunchKernelGGL(tail_kernel, dim3(B), dim3(NTHR), 0, stream,
                       partial, pos4, maskb, gcnt, gcand, out);
}

// Round 4
// 163.113 us; speedup vs baseline: 1.7921x; 1.7921x over previous
//
#include <hip/hip_runtime.h>

#define B 8
#define N 8192
#define M 2048
#define NITER 4
#define BASE_ALPHA 0.1f
#define MARGIN 0.02f           // covers fp slack (~1e-5) on the NN-invariance bound
#define CAP 16                 // candidate-list capacity (expected count ~2-3)
#define QCAP 1536              // (point,split) work-queue capacity (expected ~640)

#define NTHR 1024              // 16 waves
#define NPT 32                 // point-lanes per split
#define NSPLIT 32              // j-splits per block
#define JS (M / NSPLIT)        // 64 y's per split
#define JQ (JS / 4)            // 16 j-quads per split
#define PT 8                   // points per thread
#define PPB (NPT * PT)         // 256 points per block
#define NBLK (B * N / PPB)     // 256 blocks (iter0)

// ws layout: pos4 float4[B*N] @0 (1MB); mask u32[B*N] @1MB; cnt u32[B*N]
// @1.25MB (>CAP => tail uses mask-scan fallback); cand u16[B*N][CAP] @1.5MB
// (2MB), unordered (tail uses lex (t,j) min, so slot order is irrelevant).
// NN-invariance: computed argmin at iters 1-3 lies in {j: dist_0(j) <= d_0 +
// MARGIN}: mv = sum(alpha_i*d_i), NN-dist at step u <= d_0 - mv, excluded j
// has dist >= d_0 + MARGIN - mv => loses by >= MARGIN >> fp slack.
#define OFF_MASK  (1024 * 1024)
#define OFF_CNT   (1280 * 1024)
#define OFF_CANDL (1536 * 1024)

typedef float f2 __attribute__((ext_vector_type(2)));

// ---------------- iter 0: full scan + candidate-list emission ----------------
// R3 lesson: __launch_bounds__(1024,8) forced VGPR=32 -> pass-1 spilled to
// scratch (670 MB HBM/dispatch). (1024,4) = 128-VGPR budget, no spill.
__global__ __launch_bounds__(NTHR, 4) void iter_kernel(const float* __restrict__ pred,
                                                       const float* __restrict__ partial,
                                                       float4* __restrict__ pos4,
                                                       unsigned int* __restrict__ maskbuf,
                                                       unsigned int* __restrict__ gcnt,
                                                       unsigned short* __restrict__ gcand) {
    __shared__ float4 sX[M / 4], sY[M / 4], sZ[M / 4], sW[M / 4];  // 32 KB
    __shared__ float smint[NSPLIT][PPB];                           // 32 KB
    __shared__ float4 lpos[PPB];                                   // 4 KB
    __shared__ float thrsh[PPB];                                   // 1 KB
    __shared__ unsigned int queue[QCAP];                           // 6 KB
    __shared__ unsigned int qn;

    const int tid = threadIdx.x;
    const int b = blockIdx.x >> 5;
    const int blk = blockIdx.x & 31;
    const int gp0 = b * N + blk * PPB;

    if (tid == 0) qn = 0;

    // Build SoA tile. (-2y)*x bit-equal to reference's (-2x)*y.
    const float* pa = partial + b * M * 3;
    if (tid < M / 4) {
        int sp = tid & 31, jq = tid >> 5;
        const float* p0 = pa + (sp * JS + jq * 4) * 3;
        float a0 = p0[0], a1 = p0[1],  a2 = p0[2];
        float b0 = p0[3], b1 = p0[4],  b2 = p0[5];
        float c0 = p0[6], c1 = p0[7],  c2 = p0[8];
        float d0 = p0[9], d1 = p0[10], d2 = p0[11];
        sX[tid] = make_float4(-2.f * a0, -2.f * b0, -2.f * c0, -2.f * d0);
        sY[tid] = make_float4(-2.f * a1, -2.f * b1, -2.f * c1, -2.f * d1);
        sZ[tid] = make_float4(-2.f * a2, -2.f * b2, -2.f * c2, -2.f * d2);
        sW[tid] = make_float4(a0 * a0 + a1 * a1 + a2 * a2, b0 * b0 + b1 * b1 + b2 * b2,
                              c0 * c0 + c1 * c1 + c2 * c2, d0 * d0 + d1 * d1 + d2 * d2);
    }

    // Owners: refined_0 = pred.
    if (tid < PPB) {
        const int p = gp0 + tid;
        const float* pp = pred + (unsigned long long)p * 3;
        float rx = pp[0], ry = pp[1], rz = pp[2];
        float w = rx * rx + ry * ry + rz * rz;
        lpos[tid] = make_float4(rx, ry, rz, w);
        pos4[p] = make_float4(rx, ry, rz, w);
    }
    __syncthreads();

    const int split = tid >> 5;                    // 0..31 (uniform per half-wave)
    const int pt = tid & 31;

    // ---- pass 1: packed-f32 per-split min ----
    f2 sx[PT], sy[PT], sz[PT];
    #pragma unroll
    for (int k = 0; k < PT; ++k) {
        float4 r = lpos[pt + k * NPT];
        sx[k] = (f2){r.x, r.x}; sy[k] = (f2){r.y, r.y}; sz[k] = (f2){r.z, r.z};
    }
    f2 acc[PT];
    #pragma unroll
    for (int k = 0; k < PT; ++k) acc[k] = (f2){3.402823466e+38f, 3.402823466e+38f};

    #pragma unroll 2
    for (int jq = 0; jq < JQ; ++jq) {
        float4 qx = sX[jq * 32 + split], qy = sY[jq * 32 + split];
        float4 qz = sZ[jq * 32 + split], qw = sW[jq * 32 + split];
        f2 qx01 = (f2){qx.x, qx.y}, qx23 = (f2){qx.z, qx.w};
        f2 qy01 = (f2){qy.x, qy.y}, qy23 = (f2){qy.z, qy.w};
        f2 qz01 = (f2){qz.x, qz.y}, qz23 = (f2){qz.z, qz.w};
        f2 qw01 = (f2){qw.x, qw.y}, qw23 = (f2){qw.z, qw.w};
        #pragma unroll
        for (int k = 0; k < PT; ++k) {
            f2 t01 = __builtin_elementwise_fma(sx[k], qx01,
                     __builtin_elementwise_fma(sy[k], qy01,
                     __builtin_elementwise_fma(sz[k], qz01, qw01)));
            f2 t23 = __builtin_elementwise_fma(sx[k], qx23,
                     __builtin_elementwise_fma(sy[k], qy23,
                     __builtin_elementwise_fma(sz[k], qz23, qw23)));
            acc[k] = __builtin_elementwise_min(acc[k],
                     __builtin_elementwise_min(t01, t23));     // exact, order-invariant
        }
    }
    #pragma unroll
    for (int k = 0; k < PT; ++k)
        smint[split][pt + k * NPT] = fminf(acc[k].x, acc[k].y);
    __syncthreads();

    // ---- owners: threshold + mask + (point,split) work-queue ----
    if (tid < PPB) {
        float tstar = 3.402823466e+38f;
        #pragma unroll
        for (int s = 0; s < NSPLIT; ++s) tstar = fminf(tstar, smint[s][tid]);
        const float4 f4 = lpos[tid];
        const float md = sqrtf(fmaxf(f4.w + tstar, 0.0f));
        float mdm = md + MARGIN;
        float thr = fmaf(mdm, mdm, -f4.w);         // dist<=md+MARGIN <=> t<=thr
        thrsh[tid] = thr;
        gcnt[gp0 + tid] = 0u;
        unsigned int mask = 0u;
        #pragma unroll
        for (int s = 0; s < NSPLIT; ++s) {
            if (smint[s][tid] <= thr) {
                mask |= (1u << s);
                unsigned int q = atomicAdd(&qn, 1u);
                if (q < QCAP) queue[q] = ((unsigned int)tid << 5) | (unsigned int)s;
                else gcnt[gp0 + tid] = 0x40000000u;   // queue overflow -> fallback
            }
        }
        maskbuf[gp0 + tid] = mask;
    }
    __syncthreads();

    // ---- drain queue: uniform 64-j scans, no divergence tax ----
    // Chains here only FILTER (threshold has >> fp-slack margin); tail
    // re-evaluates distances itself.
    unsigned int qc = qn; if (qc > QCAP) qc = QCAP;
    for (unsigned int e = tid; e < qc; e += NTHR) {
        unsigned int ent = queue[e];
        int p2 = (int)(ent >> 5), s = (int)(ent & 31u);
        float4 f4 = lpos[p2];
        float thr = thrsh[p2];
        unsigned int* cp = gcnt + (gp0 + p2);
        unsigned long long cb = (unsigned long long)(gp0 + p2) * CAP;
        for (int jq = 0; jq < JQ; ++jq) {
            float4 qx = sX[jq * 32 + s], qy = sY[jq * 32 + s];
            float4 qz = sZ[jq * 32 + s], qw = sW[jq * 32 + s];
            float t0 = fmaf(f4.x, qx.x, fmaf(f4.y, qy.x, fmaf(f4.z, qz.x, qw.x)));
            float t1 = fmaf(f4.x, qx.y, fmaf(f4.y, qy.y, fmaf(f4.z, qz.y, qw.y)));
            float t2 = fmaf(f4.x, qx.z, fmaf(f4.y, qy.z, fmaf(f4.z, qz.z, qw.z)));
            float t3 = fmaf(f4.x, qx.w, fmaf(f4.y, qy.w, fmaf(f4.z, qz.w, qw.w)));
            int j0 = s * JS + jq * 4;
            if (t0 <= thr) { unsigned int sl = atomicAdd(cp, 1u); if (sl < CAP) gcand[cb + sl] = (unsigned short)(j0 + 0); }
            if (t1 <= thr) { unsigned int sl = atomicAdd(cp, 1u); if (sl < CAP) gcand[cb + sl] = (unsigned short)(j0 + 1); }
            if (t2 <= thr) { unsigned int sl = atomicAdd(cp, 1u); if (sl < CAP) gcand[cb + sl] = (unsigned short)(j0 + 2); }
            if (t3 <= thr) { unsigned int sl = atomicAdd(cp, 1u); if (sl < CAP) gcand[cb + sl] = (unsigned short)(j0 + 3); }
        }
    }
}

// Rare fallback: masked-split ascending-j scan (strict < = first-argmin).
// noinline keeps the 8x-unrolled hot path small and register-light.
__device__ __attribute__((noinline)) void nn_fallback(float x, float y, float z,
                                                      unsigned int mk,
                                                      const float4* sQ,
                                                      float& bt_out, int& bj_out) {
    float bt = 3.402823466e+38f; int bj = 0;
    unsigned int m = mk;
    while (m) {
        int s = __builtin_ctz(m); m &= m - 1;
        int jb = s * JS;
        for (int jj = 0; jj < JS; ++jj) {
            int j = jb + jj;
            float4 qq = sQ[j];
            float t = fmaf(x, qq.x, fmaf(y, qq.y, fmaf(z, qq.z, qq.w)));
            if (t < bt) { bt = t; bj = j; }
        }
    }
    bt_out = bt; bj_out = bj;
}

// ---------------- iters 0..3 NN + 4 updates + final, one block per batch ----
// R3 lesson: 64+ k-indexed state regs + 8 inlined nn_eval copies => pressure.
// Keep only rx,ry,rz,md,idx (40 regs) live; mask/cnt live in LDS.
__global__ __launch_bounds__(NTHR, 4) void tail_kernel(const float* __restrict__ partial,
                                                       const float4* __restrict__ pos4,
                                                       const unsigned int* __restrict__ maskbuf,
                                                       const unsigned int* __restrict__ gcnt,
                                                       const unsigned short* __restrict__ gcand,
                                                       float* __restrict__ out) {
    __shared__ float4 sQ[M];           // (-2y0,-2y1,-2y2,|y|^2)  32 KB
    __shared__ unsigned int smk[N];    // 32 KB  per-point split mask
    __shared__ unsigned char scnt[N];  // 8 KB   per-point cand count (255 = fallback)
    __shared__ float redw[16];
    __shared__ float mxsh;

    const int tid = threadIdx.x;
    const int b = blockIdx.x;

    const float* pa = partial + b * M * 3;
    for (int j = tid; j < M; j += NTHR) {
        float a0 = pa[j * 3 + 0], a1 = pa[j * 3 + 1], a2 = pa[j * 3 + 2];
        sQ[j] = make_float4(-2.f * a0, -2.f * a1, -2.f * a2,
                            a0 * a0 + a1 * a1 + a2 * a2);
    }

    float rx[8], ry[8], rz[8], md[8];
    int idx[8];
    #pragma unroll
    for (int k = 0; k < 8; ++k) {
        int lp = k * NTHR + tid;
        int p = b * N + lp;
        float4 f = pos4[p];
        rx[k] = f.x; ry[k] = f.y; rz[k] = f.z;
        unsigned int c = gcnt[p];
        scnt[lp] = (c > CAP) ? (unsigned char)255 : (unsigned char)c;
        smk[lp] = maskbuf[p];
    }
    __syncthreads();

    // NN at x0 (list contains the argmin; same fmaf chain as pass-1 pk halves;
    // lex (t,j) min == first-argmin, order-free).
    #pragma unroll
    for (int k = 0; k < 8; ++k) {
        int lp = k * NTHR + tid;
        int p = b * N + lp;
        float x = rx[k], y = ry[k], z = rz[k];
        float w = x * x + y * y + z * z;
        float bt = 3.402823466e+38f; int bj = 0;
        int c0 = scnt[lp];
        if (c0 <= CAP) {
            const unsigned short* cp = gcand + (unsigned long long)p * CAP;
            for (int c = 0; c < c0; ++c) {
                int j = cp[c];
                float4 qq = sQ[j];
                float t = fmaf(x, qq.x, fmaf(y, qq.y, fmaf(z, qq.z, qq.w)));
                if (t < bt || (t == bt && j < bj)) { bt = t; bj = j; }
            }
        } else {
            nn_fallback(x, y, z, smk[lp], sQ, bt, bj);
        }
        md[k] = sqrtf(fmaxf(w + bt, 0.0f));
        idx[k] = bj;
    }

    for (int u = 0; u < NITER; ++u) {
        // batch max of md (exact: fmax is order-invariant)
        float vm = md[0];
        #pragma unroll
        for (int k = 1; k < 8; ++k) vm = fmaxf(vm, md[k]);
        #pragma unroll
        for (int o = 32; o > 0; o >>= 1) vm = fmaxf(vm, __shfl_xor(vm, o));
        if ((tid & 63) == 0) redw[tid >> 6] = vm;
        __syncthreads();
        if (tid == 0) {
            float v = redw[0];
            #pragma unroll
            for (int r = 1; r < 16; ++r) v = fmaxf(v, redw[r]);
            mxsh = v;
        }
        __syncthreads();

        float inv = 1.0f / (mxsh + 1e-6f);
        #pragma unroll
        for (int k = 0; k < 8; ++k) {
            int lp = k * NTHR + tid;
            int p = b * N + lp;
            float4 q = sQ[idx[k]];
            float ny0 = -0.5f * q.x;               // exact y bits
            float ny1 = -0.5f * q.y;
            float ny2 = -0.5f * q.z;
            float alpha = BASE_ALPHA * (2.0f - md[k] * inv);
            float nx = fmaf(alpha, ny0 - rx[k], rx[k]);
            float nyv = fmaf(alpha, ny1 - ry[k], ry[k]);
            float nz = fmaf(alpha, ny2 - rz[k], rz[k]);
            rx[k] = nx; ry[k] = nyv; rz[k] = nz;
            if (u < NITER - 1) {
                float w = nx * nx + nyv * nyv + nz * nz;
                float bt = 3.402823466e+38f; int bj = 0;
                int c0 = scnt[lp];
                if (c0 <= CAP) {
                    const unsigned short* cp = gcand + (unsigned long long)p * CAP;
                    for (int c = 0; c < c0; ++c) {
                        int j = cp[c];
                        float4 qq = sQ[j];
                        float t = fmaf(nx, qq.x, fmaf(nyv, qq.y, fmaf(nz, qq.z, qq.w)));
                        if (t < bt || (t == bt && j < bj)) { bt = t; bj = j; }
                    }
                } else {
                    nn_fallback(nx, nyv, nz, smk[lp], sQ, bt, bj);
                }
                md[k] = sqrtf(fmaxf(w + bt, 0.0f));
                idx[k] = bj;
            } else {
                float* po = out + (unsigned long long)p * 3;
                po[0] = nx; po[1] = nyv; po[2] = nz;
            }
        }
        __syncthreads();   // protect redw/mxsh reuse next iteration
    }
}

extern "C" void kernel_launch(void* const* d_in, const int* in_sizes, int n_in,
                              void* d_out, int out_size, void* d_ws, size_t ws_size,
                              hipStream_t stream) {
    const float* pred = (const float*)d_in[0];
    const float* partial = (const float*)d_in[1];
    char* ws = (char*)d_ws;
    float4* pos4 = (float4*)ws;
    unsigned int* maskb = (unsigned int*)(ws + OFF_MASK);
    unsigned int* gcnt = (unsigned int*)(ws + OFF_CNT);
    unsigned short* gcand = (unsigned short*)(ws + OFF_CANDL);
    float* out = (float*)d_out;

    hipLaunchKernelGGL(iter_kernel, dim3(NBLK), dim3(NTHR), 0, stream,
                       pred, partial, pos4, maskb, gcnt, gcand);
    hipLaunchKernelGGL(tail_kernel, dim3(B), dim3(NTHR), 0, stream,
                       partial, pos4, maskb, gcnt, gcand, out);
}

// Round 5
// 98.200 us; speedup vs baseline: 2.9767x; 1.6610x over previous
//
#include <hip/hip_runtime.h>

#define B 8
#define N 8192
#define M 2048
#define NITER 4
#define BASE_ALPHA 0.1f
#define MARGIN 0.02f           // covers fp slack (~1e-5) on the NN-invariance bound
#define CAP 16                 // candidate-list capacity (expected count ~2-3)

#define NTHR 1024              // 16 waves (iter0)
#define NPT 32                 // point-lanes per split
#define NSPLIT 32              // j-splits per block
#define JS (M / NSPLIT)        // 64 y's per split
#define JQ (JS / 4)            // 16 j-quads per split
#define PT 8                   // points per thread
#define PPB (NPT * PT)         // 256 points per block
#define NBLK (B * N / PPB)     // 256 blocks

#define LTHR 256               // light/final kernels: 256 blocks x 256 thr = all CUs
#define BPB 32                 // blocks per batch (light grid)

// ws: pos4 float4[B*N] @0; aux uint2[B*N] @1M (bits(md), logical idx);
// mask u32[B*N] @1.5M; cnt u32[B*N] @1.75M (>CAP => fallback);
// cand u16[B*N][CAP] @2M (2MB, ascending j); slot0 @4M, slot1 @4M+4K
// (double-buffered batch-max: kernel-boundary sync, no races).
// NN-invariance: computed argmin at iters 1-3 lies in {j: dist_0(j) <= d_0 +
// MARGIN}: mv = sum(alpha_i*d_i), NN-dist at step u <= d_0 - mv, excluded j
// has dist >= d_0 + MARGIN - mv => loses by >= MARGIN >> fp slack.
#define OFF_AUX   (1024 * 1024)
#define OFF_MASK  (1536 * 1024)
#define OFF_CNT   (1792 * 1024)
#define OFF_CANDL (2048 * 1024)
#define OFF_SLOT0 (4096 * 1024)
#define OFF_SLOT1 (4100 * 1024)

typedef float f2 __attribute__((ext_vector_type(2)));

// ---------------- iter 0: full scan, pass-2 argmin, candidate lists ----------
__global__ __launch_bounds__(NTHR, 4) void iter_kernel(const float* __restrict__ pred,
                                                       const float* __restrict__ partial,
                                                       float4* __restrict__ pos4,
                                                       uint2* __restrict__ aux,
                                                       unsigned int* __restrict__ maskbuf,
                                                       unsigned int* __restrict__ gcnt,
                                                       unsigned short* __restrict__ gcand,
                                                       float* __restrict__ slots) {
    __shared__ float4 sX[M / 4], sY[M / 4], sZ[M / 4], sW[M / 4];  // 32 KB
    __shared__ float smint[NSPLIT][PPB];                           // 32 KB
    __shared__ float4 lpos[PPB];                                   // 4 KB
    __shared__ float thrsh[PPB];                                   // 1 KB
    __shared__ unsigned int smask[PPB];                            // 1 KB
    __shared__ float redbuf[4];

    const int tid = threadIdx.x;
    const int b = blockIdx.x >> 5;
    const int blk = blockIdx.x & 31;
    const int gp0 = b * N + blk * PPB;

    // Build SoA tile. (-2y)*x bit-equal to reference's (-2x)*y.
    const float* pa = partial + b * M * 3;
    if (tid < M / 4) {
        int sp = tid & 31, jq = tid >> 5;
        const float* p0 = pa + (sp * JS + jq * 4) * 3;
        float a0 = p0[0], a1 = p0[1],  a2 = p0[2];
        float b0 = p0[3], b1 = p0[4],  b2 = p0[5];
        float c0 = p0[6], c1 = p0[7],  c2 = p0[8];
        float d0 = p0[9], d1 = p0[10], d2 = p0[11];
        sX[tid] = make_float4(-2.f * a0, -2.f * b0, -2.f * c0, -2.f * d0);
        sY[tid] = make_float4(-2.f * a1, -2.f * b1, -2.f * c1, -2.f * d1);
        sZ[tid] = make_float4(-2.f * a2, -2.f * b2, -2.f * c2, -2.f * d2);
        sW[tid] = make_float4(a0 * a0 + a1 * a1 + a2 * a2, b0 * b0 + b1 * b1 + b2 * b2,
                              c0 * c0 + c1 * c1 + c2 * c2, d0 * d0 + d1 * d1 + d2 * d2);
    }

    // Owners: refined_0 = pred.
    if (tid < PPB) {
        const int p = gp0 + tid;
        const float* pp = pred + (unsigned long long)p * 3;
        float rx = pp[0], ry = pp[1], rz = pp[2];
        float w = rx * rx + ry * ry + rz * rz;
        lpos[tid] = make_float4(rx, ry, rz, w);
        pos4[p] = make_float4(rx, ry, rz, w);
    }
    __syncthreads();

    const int split = tid >> 5;                    // 0..31 (uniform per half-wave)
    const int pt = tid & 31;

    // ---- pass 1: packed-f32 per-split min ----
    f2 sx[PT], sy[PT], sz[PT];
    #pragma unroll
    for (int k = 0; k < PT; ++k) {
        float4 r = lpos[pt + k * NPT];
        sx[k] = (f2){r.x, r.x}; sy[k] = (f2){r.y, r.y}; sz[k] = (f2){r.z, r.z};
    }
    f2 acc[PT];
    #pragma unroll
    for (int k = 0; k < PT; ++k) acc[k] = (f2){3.402823466e+38f, 3.402823466e+38f};

    #pragma unroll 2
    for (int jq = 0; jq < JQ; ++jq) {
        float4 qx = sX[jq * 32 + split], qy = sY[jq * 32 + split];
        float4 qz = sZ[jq * 32 + split], qw = sW[jq * 32 + split];
        f2 qx01 = (f2){qx.x, qx.y}, qx23 = (f2){qx.z, qx.w};
        f2 qy01 = (f2){qy.x, qy.y}, qy23 = (f2){qy.z, qy.w};
        f2 qz01 = (f2){qz.x, qz.y}, qz23 = (f2){qz.z, qz.w};
        f2 qw01 = (f2){qw.x, qw.y}, qw23 = (f2){qw.z, qw.w};
        #pragma unroll
        for (int k = 0; k < PT; ++k) {
            f2 t01 = __builtin_elementwise_fma(sx[k], qx01,
                     __builtin_elementwise_fma(sy[k], qy01,
                     __builtin_elementwise_fma(sz[k], qz01, qw01)));
            f2 t23 = __builtin_elementwise_fma(sx[k], qx23,
                     __builtin_elementwise_fma(sy[k], qy23,
                     __builtin_elementwise_fma(sz[k], qz23, qw23)));
            acc[k] = __builtin_elementwise_min(acc[k],
                     __builtin_elementwise_min(t01, t23));     // exact, order-invariant
        }
    }
    #pragma unroll
    for (int k = 0; k < PT; ++k)
        smint[split][pt + k * NPT] = fminf(acc[k].x, acc[k].y);
    __syncthreads();

    // ---- owners: lexmin split, pass-2 exact first-argmin, threshold, mask ----
    if (tid < PPB) {
        float tstar = 3.402823466e+38f; int bsplit = 0;
        #pragma unroll
        for (int s = 0; s < NSPLIT; ++s) {
            float v = smint[s][tid];
            if (v < tstar) { tstar = v; bsplit = s; }          // tie -> smaller split
        }
        const float4 f4 = lpos[tid];
        const float md = sqrtf(fmaxf(f4.w + tstar, 0.0f));
        float mdm = md + MARGIN;
        float thr = fmaf(mdm, mdm, -f4.w);         // dist<=md+MARGIN <=> t<=thr
        thrsh[tid] = thr;
        unsigned int mask = 0u;
        #pragma unroll
        for (int s = 0; s < NSPLIT; ++s)
            if (smint[s][tid] <= thr) mask |= (1u << s);
        smask[tid] = mask;
        maskbuf[gp0 + tid] = mask;

        // pass 2: scalar fmaf chain bit-identical to pk halves; earliest j wins.
        float bt = 3.402823466e+38f; int bj = 0;
        for (int jq = 0; jq < JQ; ++jq) {
            float4 qx = sX[jq * 32 + bsplit], qy = sY[jq * 32 + bsplit];
            float4 qz = sZ[jq * 32 + bsplit], qw = sW[jq * 32 + bsplit];
            float t0 = fmaf(f4.x, qx.x, fmaf(f4.y, qy.x, fmaf(f4.z, qz.x, qw.x)));
            float t1 = fmaf(f4.x, qx.y, fmaf(f4.y, qy.y, fmaf(f4.z, qz.y, qw.y)));
            float t2 = fmaf(f4.x, qx.z, fmaf(f4.y, qy.z, fmaf(f4.z, qz.z, qw.z)));
            float t3 = fmaf(f4.x, qx.w, fmaf(f4.y, qy.w, fmaf(f4.z, qz.w, qw.w)));
            if (t0 < bt) { bt = t0; bj = jq * 4 + 0; }
            if (t1 < bt) { bt = t1; bj = jq * 4 + 1; }
            if (t2 < bt) { bt = t2; bj = jq * 4 + 2; }
            if (t3 < bt) { bt = t3; bj = jq * 4 + 3; }
        }
        aux[gp0 + tid] = make_uint2(__float_as_uint(md),
                                    (unsigned int)(bsplit * JS + bj));   // logical idx

        float wm = md;
        #pragma unroll
        for (int o = 32; o > 0; o >>= 1) wm = fmaxf(wm, __shfl_down(wm, o));
        if ((tid & 63) == 0) redbuf[tid >> 6] = wm;
    }
    __syncthreads();
    if (tid == 0)
        slots[b * BPB + blk] = fmaxf(fmaxf(redbuf[0], redbuf[1]),
                                     fmaxf(redbuf[2], redbuf[3]));

    // ---- candidate collection: wave-per-point, uniform control, atomic-free ----
    // Wave w handles points w*16..w*16+15. Per masked split s (wave-uniform
    // ctz loop), lane l evaluates j = s*64+l; ballot+prefix compacts hits into
    // gcand in ascending-j order. Chain only FILTERS (MARGIN >> fp slack).
    {
        const int lane = tid & 63;
        const int wv = tid >> 6;                   // 0..15
        const unsigned long long lmask = (1ull << lane) - 1ull;
        const int jq2 = lane >> 2, c2 = lane & 3;
        for (int q0 = 0; q0 < 16; ++q0) {
            int q = wv * 16 + q0;
            float4 f4 = lpos[q];                   // broadcast reads
            float thr = thrsh[q];
            unsigned int m = smask[q];             // wave-uniform
            int cnt = 0;
            unsigned long long cb = (unsigned long long)(gp0 + q) * CAP;
            while (m) {
                int s = __builtin_ctz(m); m &= m - 1;
                int e = (jq2 * 32 + s) * 4 + c2;   // element j = s*64 + lane
                float qx = ((const float*)sX)[e];
                float qy = ((const float*)sY)[e];
                float qz = ((const float*)sZ)[e];
                float qw = ((const float*)sW)[e];
                float t = fmaf(f4.x, qx, fmaf(f4.y, qy, fmaf(f4.z, qz, qw)));
                bool hit = (t <= thr);
                unsigned long long bal = __ballot(hit);
                int pos = cnt + (int)__popcll(bal & lmask);
                if (hit && pos < CAP)
                    gcand[cb + pos] = (unsigned short)(s * JS + lane);
                cnt += (int)__popcll(bal);
            }
            if (lane == 0) gcnt[gp0 + q] = (unsigned int)cnt;
        }
    }
}

// Rare fallback: masked-split ascending-j scan from global partial
// (strict < = first-argmin; chain verbatim: -2y / |y|^2 recompute is exact).
__device__ __attribute__((noinline)) void nn_fallback(float x, float y, float z,
                                                      unsigned int mk,
                                                      const float* __restrict__ pa,
                                                      float& bt_out, int& bj_out) {
    float bt = 3.402823466e+38f; int bj = 0;
    unsigned int m = mk;
    while (m) {
        int s = __builtin_ctz(m); m &= m - 1;
        int jb = s * JS;
        for (int jj = 0; jj < JS; ++jj) {
            int j = jb + jj;
            const float* py = pa + j * 3;
            float y0 = py[0], y1 = py[1], y2 = py[2];
            float qx = -2.f * y0, qy = -2.f * y1, qz = -2.f * y2;
            float qw = y0 * y0 + y1 * y1 + y2 * y2;
            float t = fmaf(x, qx, fmaf(y, qy, fmaf(z, qz, qw)));
            if (t < bt) { bt = t; bj = j; }
        }
    }
    bt_out = bt; bj_out = bj;
}

// ---------------- iters 1..3: update + candidate NN, full-GPU grid ----------
__global__ __launch_bounds__(LTHR) void light_kernel(const float* __restrict__ partial,
                                                     float4* __restrict__ pos4,
                                                     uint2* __restrict__ aux,
                                                     const unsigned int* __restrict__ maskbuf,
                                                     const unsigned int* __restrict__ gcnt,
                                                     const unsigned short* __restrict__ gcand,
                                                     const float* __restrict__ slots_in,
                                                     float* __restrict__ slots_out) {
    __shared__ float redbuf[4];
    __shared__ float mxsh;

    const int tid = threadIdx.x;
    const int p = blockIdx.x * LTHR + tid;         // batch uniform per block
    const int b = p >> 13;
    const int blk = blockIdx.x & 31;
    const float* pa = partial + b * M * 3;

    if (tid < 64) {
        float v = slots_in[b * BPB + (tid & 31)];
        #pragma unroll
        for (int o = 16; o > 0; o >>= 1) v = fmaxf(v, __shfl_xor(v, o));
        if (tid == 0) mxsh = v;
    }
    __syncthreads();

    float4 f = pos4[p];
    uint2 a = aux[p];
    float md = __uint_as_float(a.x);
    unsigned int cnt = gcnt[p];

    // update (verbatim chains; raw partial read == -0.5*(-2y) bits)
    const float* py = pa + (int)a.y * 3;
    float y0 = py[0], y1 = py[1], y2 = py[2];
    float inv = 1.0f / (mxsh + 1e-6f);
    float alpha = BASE_ALPHA * (2.0f - md * inv);
    float nx = fmaf(alpha, y0 - f.x, f.x);
    float ny = fmaf(alpha, y1 - f.y, f.y);
    float nz = fmaf(alpha, y2 - f.z, f.z);
    float w = nx * nx + ny * ny + nz * nz;
    pos4[p] = make_float4(nx, ny, nz, w);

    // NN over candidate list (ascending j; lex (t,j) min == first-argmin)
    float bt = 3.402823466e+38f; int bj = 0;
    if (cnt <= CAP) {
        const unsigned short* cp = gcand + (unsigned long long)p * CAP;
        for (unsigned int c = 0; c < cnt; ++c) {
            int j = cp[c];
            const float* pj = pa + j * 3;
            float a0 = pj[0], a1 = pj[1], a2 = pj[2];
            float qx = -2.f * a0, qy = -2.f * a1, qz = -2.f * a2;
            float qw = a0 * a0 + a1 * a1 + a2 * a2;
            float t = fmaf(nx, qx, fmaf(ny, qy, fmaf(nz, qz, qw)));
            if (t < bt || (t == bt && j < bj)) { bt = t; bj = j; }
        }
    } else {
        nn_fallback(nx, ny, nz, maskbuf[p], pa, bt, bj);
    }
    float mdn = sqrtf(fmaxf(w + bt, 0.0f));
    aux[p] = make_uint2(__float_as_uint(mdn), (unsigned int)bj);

    float wm = mdn;
    #pragma unroll
    for (int o = 32; o > 0; o >>= 1) wm = fmaxf(wm, __shfl_down(wm, o));
    if ((tid & 63) == 0) redbuf[tid >> 6] = wm;
    __syncthreads();
    if (tid == 0)
        slots_out[b * BPB + blk] = fmaxf(fmaxf(redbuf[0], redbuf[1]),
                                         fmaxf(redbuf[2], redbuf[3]));
}

__global__ __launch_bounds__(LTHR) void final_kernel(const float* __restrict__ partial,
                                                     const float4* __restrict__ pos4,
                                                     const uint2* __restrict__ aux,
                                                     const float* __restrict__ slots,
                                                     float* __restrict__ out) {
    __shared__ float mxsh;
    const int p = blockIdx.x * LTHR + threadIdx.x; // batch uniform per block
    const int b = p >> 13;
    if (threadIdx.x < 64) {
        float v = slots[b * BPB + (threadIdx.x & 31)];
        #pragma unroll
        for (int o = 16; o > 0; o >>= 1) v = fmaxf(v, __shfl_xor(v, o));
        if (threadIdx.x == 0) mxsh = v;
    }
    __syncthreads();
    float4 f = pos4[p];
    uint2 a = aux[p];
    float md = __uint_as_float(a.x);
    const float* py = partial + ((unsigned long long)(b * M + (int)a.y)) * 3;
    float y0 = py[0], y1 = py[1], y2 = py[2];      // same bits as -0.5*(-2y)
    float inv = 1.0f / (mxsh + 1e-6f);
    float alpha = BASE_ALPHA * (2.0f - md * inv);
    float* po = out + (unsigned long long)p * 3;
    po[0] = fmaf(alpha, y0 - f.x, f.x);
    po[1] = fmaf(alpha, y1 - f.y, f.y);
    po[2] = fmaf(alpha, y2 - f.z, f.z);
}

extern "C" void kernel_launch(void* const* d_in, const int* in_sizes, int n_in,
                              void* d_out, int out_size, void* d_ws, size_t ws_size,
                              hipStream_t stream) {
    const float* pred = (const float*)d_in[0];
    const float* partial = (const float*)d_in[1];
    char* ws = (char*)d_ws;
    float4* pos4 = (float4*)ws;
    uint2* aux = (uint2*)(ws + OFF_AUX);
    unsigned int* maskb = (unsigned int*)(ws + OFF_MASK);
    unsigned int* gcnt = (unsigned int*)(ws + OFF_CNT);
    unsigned short* gcand = (unsigned short*)(ws + OFF_CANDL);
    float* slot0 = (float*)(ws + OFF_SLOT0);
    float* slot1 = (float*)(ws + OFF_SLOT1);
    float* out = (float*)d_out;

    hipLaunchKernelGGL(iter_kernel, dim3(NBLK), dim3(NTHR), 0, stream,
                       pred, partial, pos4, aux, maskb, gcnt, gcand, slot0);
    hipLaunchKernelGGL(light_kernel, dim3(B * N / LTHR), dim3(LTHR), 0, stream,
                       partial, pos4, aux, maskb, gcnt, gcand, slot0, slot1);
    hipLaunchKernelGGL(light_kernel, dim3(B * N / LTHR), dim3(LTHR), 0, stream,
                       partial, pos4, aux, maskb, gcnt, gcand, slot1, slot0);
    hipLaunchKernelGGL(light_kernel, dim3(B * N / LTHR), dim3(LTHR), 0, stream,
                       partial, pos4, aux, maskb, gcnt, gcand, slot0, slot1);
    hipLaunchKernelGGL(final_kernel, dim3(B * N / LTHR), dim3(LTHR), 0, stream,
                       partial, pos4, aux, slot1, out);
}

// Round 6
// 95.822 us; speedup vs baseline: 3.0505x; 1.0248x over previous
//
#include <hip/hip_runtime.h>

#define B 8
#define N 8192
#define M 2048
#define NITER 4
#define BASE_ALPHA 0.1f
#define MARGIN 0.02f           // covers fp slack (~1e-5) on the NN-invariance bound
#define CAP 16                 // candidate-list capacity (expected count ~2-3)
#define SELF 0.69f             // batch-max selection: < (0.8/0.9)^3 = 0.70233
#define SELCAP 1024            // selected-point cap per batch (overflow -> full path)

#define NTHR 1024              // 16 waves (iter0 / traj)
#define NPT 32                 // point-lanes per split
#define NSPLIT 32              // j-splits per block
#define JS (M / NSPLIT)        // 64 y's per split
#define JQ (JS / 4)            // 16 j-quads per split
#define PT 8                   // points per thread
#define PPB (NPT * PT)         // 256 points per block
#define NBLK (B * N / PPB)     // 256 blocks

#define LTHR 256               // fused tail: 256 blocks x 256 thr = all CUs

// ws: pos4 float4[B*N] @0; aux uint2[B*N] @1M (bits(md0), logical idx0);
// mask u32[B*N] @1.5M; cnt u32[B*N] @1.75M (>CAP => fallback);
// cand u16[B*N][CAP] @2M (ascending j); traj float[B][NITER] @4M (mx_0..mx_3).
// NN-invariance (candidates): argmin at iters 1-3 lies in {j: dist_0(j) <=
// d_0 + MARGIN}. Batch-max invariance: md^{u+1} = (1-alpha_u) md^u exactly in
// R (move is toward the current NN; triangle ineq bounds all others below by
// the same), alpha in [0.1,0.2] => argmax at u<=3 has md_0 >= 0.7023*mx_0;
// select >= 0.69*mx_0 (1.8% margin >> fp slack ~1e-5).
#define OFF_AUX   (1024 * 1024)
#define OFF_MASK  (1536 * 1024)
#define OFF_CNT   (1792 * 1024)
#define OFF_CANDL (2048 * 1024)
#define OFF_TRAJ  (4096 * 1024)

typedef float f2 __attribute__((ext_vector_type(2)));

// ---------------- iter 0: full scan, pass-2 argmin, candidate lists ----------
__global__ __launch_bounds__(NTHR, 4) void iter_kernel(const float* __restrict__ pred,
                                                       const float* __restrict__ partial,
                                                       float4* __restrict__ pos4,
                                                       uint2* __restrict__ aux,
                                                       unsigned int* __restrict__ maskbuf,
                                                       unsigned int* __restrict__ gcnt,
                                                       unsigned short* __restrict__ gcand) {
    __shared__ float4 sX[M / 4], sY[M / 4], sZ[M / 4], sW[M / 4];  // 32 KB
    __shared__ float smint[NSPLIT][PPB];                           // 32 KB
    __shared__ float4 lpos[PPB];                                   // 4 KB
    __shared__ float thrsh[PPB];                                   // 1 KB
    __shared__ unsigned int smask[PPB];                            // 1 KB

    const int tid = threadIdx.x;
    const int b = blockIdx.x >> 5;
    const int blk = blockIdx.x & 31;
    const int gp0 = b * N + blk * PPB;

    // Build SoA tile. (-2y)*x bit-equal to reference's (-2x)*y.
    const float* pa = partial + b * M * 3;
    if (tid < M / 4) {
        int sp = tid & 31, jq = tid >> 5;
        const float* p0 = pa + (sp * JS + jq * 4) * 3;
        float a0 = p0[0], a1 = p0[1],  a2 = p0[2];
        float b0 = p0[3], b1 = p0[4],  b2 = p0[5];
        float c0 = p0[6], c1 = p0[7],  c2 = p0[8];
        float d0 = p0[9], d1 = p0[10], d2 = p0[11];
        sX[tid] = make_float4(-2.f * a0, -2.f * b0, -2.f * c0, -2.f * d0);
        sY[tid] = make_float4(-2.f * a1, -2.f * b1, -2.f * c1, -2.f * d1);
        sZ[tid] = make_float4(-2.f * a2, -2.f * b2, -2.f * c2, -2.f * d2);
        sW[tid] = make_float4(a0 * a0 + a1 * a1 + a2 * a2, b0 * b0 + b1 * b1 + b2 * b2,
                              c0 * c0 + c1 * c1 + c2 * c2, d0 * d0 + d1 * d1 + d2 * d2);
    }

    // Owners: refined_0 = pred.
    if (tid < PPB) {
        const int p = gp0 + tid;
        const float* pp = pred + (unsigned long long)p * 3;
        float rx = pp[0], ry = pp[1], rz = pp[2];
        float w = rx * rx + ry * ry + rz * rz;
        lpos[tid] = make_float4(rx, ry, rz, w);
        pos4[p] = make_float4(rx, ry, rz, w);
    }
    __syncthreads();

    const int split = tid >> 5;                    // 0..31 (uniform per half-wave)
    const int pt = tid & 31;

    // ---- pass 1: packed-f32 per-split min ----
    f2 sx[PT], sy[PT], sz[PT];
    #pragma unroll
    for (int k = 0; k < PT; ++k) {
        float4 r = lpos[pt + k * NPT];
        sx[k] = (f2){r.x, r.x}; sy[k] = (f2){r.y, r.y}; sz[k] = (f2){r.z, r.z};
    }
    f2 acc[PT];
    #pragma unroll
    for (int k = 0; k < PT; ++k) acc[k] = (f2){3.402823466e+38f, 3.402823466e+38f};

    #pragma unroll 2
    for (int jq = 0; jq < JQ; ++jq) {
        float4 qx = sX[jq * 32 + split], qy = sY[jq * 32 + split];
        float4 qz = sZ[jq * 32 + split], qw = sW[jq * 32 + split];
        f2 qx01 = (f2){qx.x, qx.y}, qx23 = (f2){qx.z, qx.w};
        f2 qy01 = (f2){qy.x, qy.y}, qy23 = (f2){qy.z, qy.w};
        f2 qz01 = (f2){qz.x, qz.y}, qz23 = (f2){qz.z, qz.w};
        f2 qw01 = (f2){qw.x, qw.y}, qw23 = (f2){qw.z, qw.w};
        #pragma unroll
        for (int k = 0; k < PT; ++k) {
            f2 t01 = __builtin_elementwise_fma(sx[k], qx01,
                     __builtin_elementwise_fma(sy[k], qy01,
                     __builtin_elementwise_fma(sz[k], qz01, qw01)));
            f2 t23 = __builtin_elementwise_fma(sx[k], qx23,
                     __builtin_elementwise_fma(sy[k], qy23,
                     __builtin_elementwise_fma(sz[k], qz23, qw23)));
            acc[k] = __builtin_elementwise_min(acc[k],
                     __builtin_elementwise_min(t01, t23));     // exact, order-invariant
        }
    }
    #pragma unroll
    for (int k = 0; k < PT; ++k)
        smint[split][pt + k * NPT] = fminf(acc[k].x, acc[k].y);
    __syncthreads();

    // ---- owners: lexmin split, pass-2 exact first-argmin, threshold, mask ----
    if (tid < PPB) {
        float tstar = 3.402823466e+38f; int bsplit = 0;
        #pragma unroll
        for (int s = 0; s < NSPLIT; ++s) {
            float v = smint[s][tid];
            if (v < tstar) { tstar = v; bsplit = s; }          // tie -> smaller split
        }
        const float4 f4 = lpos[tid];
        const float md = sqrtf(fmaxf(f4.w + tstar, 0.0f));
        float mdm = md + MARGIN;
        float thr = fmaf(mdm, mdm, -f4.w);         // dist<=md+MARGIN <=> t<=thr
        thrsh[tid] = thr;
        unsigned int mask = 0u;
        #pragma unroll
        for (int s = 0; s < NSPLIT; ++s)
            if (smint[s][tid] <= thr) mask |= (1u << s);
        smask[tid] = mask;
        maskbuf[gp0 + tid] = mask;

        // pass 2: scalar fmaf chain bit-identical to pk halves; earliest j wins.
        float bt = 3.402823466e+38f; int bj = 0;
        for (int jq = 0; jq < JQ; ++jq) {
            float4 qx = sX[jq * 32 + bsplit], qy = sY[jq * 32 + bsplit];
            float4 qz = sZ[jq * 32 + bsplit], qw = sW[jq * 32 + bsplit];
            float t0 = fmaf(f4.x, qx.x, fmaf(f4.y, qy.x, fmaf(f4.z, qz.x, qw.x)));
            float t1 = fmaf(f4.x, qx.y, fmaf(f4.y, qy.y, fmaf(f4.z, qz.y, qw.y)));
            float t2 = fmaf(f4.x, qx.z, fmaf(f4.y, qy.z, fmaf(f4.z, qz.z, qw.z)));
            float t3 = fmaf(f4.x, qx.w, fmaf(f4.y, qy.w, fmaf(f4.z, qz.w, qw.w)));
            if (t0 < bt) { bt = t0; bj = jq * 4 + 0; }
            if (t1 < bt) { bt = t1; bj = jq * 4 + 1; }
            if (t2 < bt) { bt = t2; bj = jq * 4 + 2; }
            if (t3 < bt) { bt = t3; bj = jq * 4 + 3; }
        }
        aux[gp0 + tid] = make_uint2(__float_as_uint(md),
                                    (unsigned int)(bsplit * JS + bj));   // logical idx
    }
    __syncthreads();

    // ---- candidate collection: wave-per-point, uniform control, atomic-free ----
    // Wave w handles points w*16..w*16+15. Per masked split s (wave-uniform
    // ctz loop), lane l evaluates j = s*64+l; ballot+prefix compacts hits into
    // gcand in ascending-j order. Chain only FILTERS (MARGIN >> fp slack).
    {
        const int lane = tid & 63;
        const int wv = tid >> 6;                   // 0..15
        const unsigned long long lmask = (1ull << lane) - 1ull;
        const int jq2 = lane >> 2, c2 = lane & 3;
        for (int q0 = 0; q0 < 16; ++q0) {
            int q = wv * 16 + q0;
            float4 f4 = lpos[q];                   // broadcast reads
            float thr = thrsh[q];
            unsigned int m = smask[q];             // wave-uniform
            int cnt = 0;
            unsigned long long cb = (unsigned long long)(gp0 + q) * CAP;
            while (m) {
                int s = __builtin_ctz(m); m &= m - 1;
                int e = (jq2 * 32 + s) * 4 + c2;   // element j = s*64 + lane
                float qx = ((const float*)sX)[e];
                float qy = ((const float*)sY)[e];
                float qz = ((const float*)sZ)[e];
                float qw = ((const float*)sW)[e];
                float t = fmaf(f4.x, qx, fmaf(f4.y, qy, fmaf(f4.z, qz, qw)));
                bool hit = (t <= thr);
                unsigned long long bal = __ballot(hit);
                int pos = cnt + (int)__popcll(bal & lmask);
                if (hit && pos < CAP)
                    gcand[cb + pos] = (unsigned short)(s * JS + lane);
                cnt += (int)__popcll(bal);
            }
            if (lane == 0) gcnt[gp0 + q] = (unsigned int)cnt;
        }
    }
}

// LDS-tile fallback NN: masked-split ascending scan (strict < = first-argmin).
__device__ __forceinline__ void nn_fb_lds(float x, float y, float z,
                                          unsigned int mk, const float4* sQ,
                                          float& bt_out, int& bj_out) {
    float bt = 3.402823466e+38f; int bj = 0;
    unsigned int m = mk;
    while (m) {
        int s = __builtin_ctz(m); m &= m - 1;
        int jb = s * JS;
        for (int jj = 0; jj < JS; ++jj) {
            int j = jb + jj;
            float4 qq = sQ[j];
            float t = fmaf(x, qq.x, fmaf(y, qq.y, fmaf(z, qq.z, qq.w)));
            if (t < bt) { bt = t; bj = j; }
        }
    }
    bt_out = bt; bj_out = bj;
}

// Global-gather fallback NN (verbatim R5 chain).
__device__ __attribute__((noinline)) void nn_fb_g(float x, float y, float z,
                                                  unsigned int mk,
                                                  const float* __restrict__ pa,
                                                  float& bt_out, int& bj_out) {
    float bt = 3.402823466e+38f; int bj = 0;
    unsigned int m = mk;
    while (m) {
        int s = __builtin_ctz(m); m &= m - 1;
        int jb = s * JS;
        for (int jj = 0; jj < JS; ++jj) {
            int j = jb + jj;
            const float* py = pa + j * 3;
            float y0 = py[0], y1 = py[1], y2 = py[2];
            float qx = -2.f * y0, qy = -2.f * y1, qz = -2.f * y2;
            float qw = y0 * y0 + y1 * y1 + y2 * y2;
            float t = fmaf(x, qx, fmaf(y, qy, fmaf(z, qz, qw)));
            if (t < bt) { bt = t; bj = j; }
        }
    }
    bt_out = bt; bj_out = bj;
}

// ---------------- batch-max trajectory: one block per batch --------------
// Computes mx_0..mx_3 exactly by replaying verbatim chains for the points
// that can ever achieve the batch max (md_0 >= SELF*mx_0; proof in header).
__global__ __launch_bounds__(NTHR, 2) void traj_kernel(const float* __restrict__ partial,
                                                       const float4* __restrict__ pos4,
                                                       const uint2* __restrict__ aux,
                                                       const unsigned int* __restrict__ maskbuf,
                                                       const unsigned int* __restrict__ gcnt,
                                                       const unsigned short* __restrict__ gcand,
                                                       float* __restrict__ traj) {
    __shared__ float4 sQ[M];                       // 32 KB
    __shared__ unsigned short slist[SELCAP];       // 2 KB
    __shared__ float redw[16];
    __shared__ float smx[NITER];
    __shared__ unsigned int snsel;
    __shared__ int sovf;

    const int tid = threadIdx.x;
    const int b = blockIdx.x;
    if (tid == 0) { snsel = 0; sovf = 0; }

    const float* pa = partial + b * M * 3;
    for (int j = tid; j < M; j += NTHR) {
        float a0 = pa[j * 3 + 0], a1 = pa[j * 3 + 1], a2 = pa[j * 3 + 2];
        sQ[j] = make_float4(-2.f * a0, -2.f * a1, -2.f * a2,
                            a0 * a0 + a1 * a1 + a2 * a2);
    }

    // mx_0 = exact max over all md_0 (fmax order-invariant).
    float md0k[8];
    float vm = 0.0f;
    #pragma unroll
    for (int k = 0; k < 8; ++k) {
        md0k[k] = __uint_as_float(aux[b * N + k * NTHR + tid].x);
        vm = fmaxf(vm, md0k[k]);
    }
    #pragma unroll
    for (int o = 32; o > 0; o >>= 1) vm = fmaxf(vm, __shfl_xor(vm, o));
    if ((tid & 63) == 0) redw[tid >> 6] = vm;
    __syncthreads();
    if (tid == 0) {
        float v = redw[0];
        #pragma unroll
        for (int r = 1; r < 16; ++r) v = fmaxf(v, redw[r]);
        smx[0] = v;
    }
    __syncthreads();
    const float thrsel = SELF * smx[0];

    #pragma unroll
    for (int k = 0; k < 8; ++k) {
        if (md0k[k] >= thrsel) {
            unsigned int pos = atomicAdd(&snsel, 1u);
            if (pos < SELCAP) slist[pos] = (unsigned short)(k * NTHR + tid);
            else sovf = 1;
        }
    }
    __syncthreads();
    const unsigned int nsel = snsel;
    const bool ovfl = (nsel > SELCAP) || (sovf != 0);   // block-uniform

    if (!ovfl) {
        const bool has = tid < (int)nsel;
        float x = 0.f, y = 0.f, z = 0.f, md = 0.f;
        int idx = 0, p = 0;
        unsigned int cnt = 0, mk = 0;
        if (has) {
            int lp = slist[tid];
            p = b * N + lp;
            float4 f = pos4[p];
            x = f.x; y = f.y; z = f.z;
            uint2 a = aux[p];
            md = __uint_as_float(a.x); idx = (int)a.y;
            cnt = gcnt[p];
            if (cnt > CAP) mk = maskbuf[p];
        }
        for (int u = 1; u < NITER; ++u) {
            float inv = 1.0f / (smx[u - 1] + 1e-6f);
            float mdn = 0.0f;
            if (has) {
                float4 q = sQ[idx];
                float y0 = -0.5f * q.x, y1 = -0.5f * q.y, y2 = -0.5f * q.z;  // exact y bits
                float alpha = BASE_ALPHA * (2.0f - md * inv);
                x = fmaf(alpha, y0 - x, x);
                y = fmaf(alpha, y1 - y, y);
                z = fmaf(alpha, y2 - z, z);
                float w = x * x + y * y + z * z;
                float bt = 3.402823466e+38f; int bj = 0;
                if (cnt <= CAP) {
                    const unsigned short* cp = gcand + (unsigned long long)p * CAP;
                    for (unsigned int c = 0; c < cnt; ++c) {
                        int j = cp[c];
                        float4 qq = sQ[j];
                        float t = fmaf(x, qq.x, fmaf(y, qq.y, fmaf(z, qq.z, qq.w)));
                        if (t < bt || (t == bt && j < bj)) { bt = t; bj = j; }
                    }
                } else {
                    nn_fb_lds(x, y, z, mk, sQ, bt, bj);
                }
                md = sqrtf(fmaxf(w + bt, 0.0f));
                idx = bj;
                mdn = md;
            }
            #pragma unroll
            for (int o = 32; o > 0; o >>= 1) mdn = fmaxf(mdn, __shfl_xor(mdn, o));
            if ((tid & 63) == 0) redw[tid >> 6] = mdn;
            __syncthreads();
            if (tid == 0) {
                float v = redw[0];
                #pragma unroll
                for (int r = 1; r < 16; ++r) v = fmaxf(v, redw[r]);
                smx[u] = v;
            }
            __syncthreads();
        }
    } else {
        // Rare exact full-batch trajectory (e.g. degenerate data).
        float xs[8], ys[8], zs[8], mds[8];
        int idxs[8];
        #pragma unroll
        for (int k = 0; k < 8; ++k) {
            int p = b * N + k * NTHR + tid;
            float4 f = pos4[p];
            xs[k] = f.x; ys[k] = f.y; zs[k] = f.z;
            uint2 a = aux[p];
            mds[k] = __uint_as_float(a.x); idxs[k] = (int)a.y;
        }
        for (int u = 1; u < NITER; ++u) {
            float inv = 1.0f / (smx[u - 1] + 1e-6f);
            float vmx = 0.0f;
            #pragma unroll
            for (int k = 0; k < 8; ++k) {
                int p = b * N + k * NTHR + tid;
                float4 q = sQ[idxs[k]];
                float y0 = -0.5f * q.x, y1 = -0.5f * q.y, y2 = -0.5f * q.z;
                float alpha = BASE_ALPHA * (2.0f - mds[k] * inv);
                float nx = fmaf(alpha, y0 - xs[k], xs[k]);
                float ny = fmaf(alpha, y1 - ys[k], ys[k]);
                float nz = fmaf(alpha, y2 - zs[k], zs[k]);
                xs[k] = nx; ys[k] = ny; zs[k] = nz;
                float w = nx * nx + ny * ny + nz * nz;
                float bt = 3.402823466e+38f; int bj = 0;
                unsigned int cnt = gcnt[p];
                if (cnt <= CAP) {
                    const unsigned short* cp = gcand + (unsigned long long)p * CAP;
                    for (unsigned int c = 0; c < cnt; ++c) {
                        int j = cp[c];
                        float4 qq = sQ[j];
                        float t = fmaf(nx, qq.x, fmaf(ny, qq.y, fmaf(nz, qq.z, qq.w)));
                        if (t < bt || (t == bt && j < bj)) { bt = t; bj = j; }
                    }
                } else {
                    nn_fb_lds(nx, ny, nz, maskbuf[p], sQ, bt, bj);
                }
                mds[k] = sqrtf(fmaxf(w + bt, 0.0f));
                idxs[k] = bj;
                vmx = fmaxf(vmx, mds[k]);
            }
            #pragma unroll
            for (int o = 32; o > 0; o >>= 1) vmx = fmaxf(vmx, __shfl_xor(vmx, o));
            if ((tid & 63) == 0) redw[tid >> 6] = vmx;
            __syncthreads();
            if (tid == 0) {
                float v = redw[0];
                #pragma unroll
                for (int r = 1; r < 16; ++r) v = fmaxf(v, redw[r]);
                smx[u] = v;
            }
            __syncthreads();
        }
    }
    if (tid < NITER) traj[b * NITER + tid] = smx[tid];
}

// ---------------- fused iters 1..3 + final: all in registers ----------------
__global__ __launch_bounds__(LTHR) void fused_tail(const float* __restrict__ partial,
                                                   const float4* __restrict__ pos4,
                                                   const uint2* __restrict__ aux,
                                                   const unsigned int* __restrict__ maskbuf,
                                                   const unsigned int* __restrict__ gcnt,
                                                   const unsigned short* __restrict__ gcand,
                                                   const float* __restrict__ traj,
                                                   float* __restrict__ out) {
    const int p = blockIdx.x * LTHR + threadIdx.x;     // batch uniform per block
    const int b = p >> 13;
    const float* pa = partial + b * M * 3;

    float mx0 = traj[b * NITER + 0];
    float mx1 = traj[b * NITER + 1];
    float mx2 = traj[b * NITER + 2];
    float mx3 = traj[b * NITER + 3];

    float4 f = pos4[p];
    uint2 a = aux[p];
    float x = f.x, y = f.y, z = f.z;
    float md = __uint_as_float(a.x);
    int idx = (int)a.y;
    unsigned int cnt = gcnt[p];
    unsigned int mk = (cnt > CAP) ? maskbuf[p] : 0u;
    const unsigned short* cp = gcand + (unsigned long long)p * CAP;

    #pragma unroll
    for (int u = 1; u < NITER; ++u) {
        float mx = (u == 1) ? mx0 : ((u == 2) ? mx1 : mx2);
        float inv = 1.0f / (mx + 1e-6f);
        const float* py = pa + idx * 3;
        float y0 = py[0], y1 = py[1], y2 = py[2];      // same bits as -0.5*(-2y)
        float alpha = BASE_ALPHA * (2.0f - md * inv);
        x = fmaf(alpha, y0 - x, x);
        y = fmaf(alpha, y1 - y, y);
        z = fmaf(alpha, y2 - z, z);
        float w = x * x + y * y + z * z;

        float bt = 3.402823466e+38f; int bj = 0;
        if (cnt <= CAP) {
            for (unsigned int c = 0; c < cnt; ++c) {
                int j = cp[c];
                const float* pj = pa + j * 3;
                float a0 = pj[0], a1 = pj[1], a2 = pj[2];
                float qx = -2.f * a0, qy = -2.f * a1, qz = -2.f * a2;
                float qw = a0 * a0 + a1 * a1 + a2 * a2;
                float t = fmaf(x, qx, fmaf(y, qy, fmaf(z, qz, qw)));
                if (t < bt || (t == bt && j < bj)) { bt = t; bj = j; }
            }
        } else {
            nn_fb_g(x, y, z, mk, pa, bt, bj);
        }
        md = sqrtf(fmaxf(w + bt, 0.0f));
        idx = bj;
    }

    // final update (verbatim final_kernel chain)
    {
        float inv = 1.0f / (mx3 + 1e-6f);
        const float* py = pa + idx * 3;
        float y0 = py[0], y1 = py[1], y2 = py[2];
        float alpha = BASE_ALPHA * (2.0f - md * inv);
        float* po = out + (unsigned long long)p * 3;
        po[0] = fmaf(alpha, y0 - x, x);
        po[1] = fmaf(alpha, y1 - y, y);
        po[2] = fmaf(alpha, y2 - z, z);
    }
}

extern "C" void kernel_launch(void* const* d_in, const int* in_sizes, int n_in,
                              void* d_out, int out_size, void* d_ws, size_t ws_size,
                              hipStream_t stream) {
    const float* pred = (const float*)d_in[0];
    const float* partial = (const float*)d_in[1];
    char* ws = (char*)d_ws;
    float4* pos4 = (float4*)ws;
    uint2* aux = (uint2*)(ws + OFF_AUX);
    unsigned int* maskb = (unsigned int*)(ws + OFF_MASK);
    unsigned int* gcnt = (unsigned int*)(ws + OFF_CNT);
    unsigned short* gcand = (unsigned short*)(ws + OFF_CANDL);
    float* traj = (float*)(ws + OFF_TRAJ);
    float* out = (float*)d_out;

    hipLaunchKernelGGL(iter_kernel, dim3(NBLK), dim3(NTHR), 0, stream,
                       pred, partial, pos4, aux, maskb, gcnt, gcand);
    hipLaunchKernelGGL(traj_kernel, dim3(B), dim3(NTHR), 0, stream,
                       partial, pos4, aux, maskb, gcnt, gcand, traj);
    hipLaunchKernelGGL(fused_tail, dim3(B * N / LTHR), dim3(LTHR), 0, stream,
                       partial, pos4, aux, maskb, gcnt, gcand, traj, out);
}